// Round 2
// baseline (399.313 us; speedup 1.0000x reference)
//
#include <hip/hip_runtime.h>
#include <hip/hip_bf16.h>
#include <stdint.h>

// Problem: B=8192, D=1024, H=1024. Fused gates GEMM: M=8192, N=4*1024, K=2048
// (K = concat [x | h_prev], weights [Wx | Wh]), then elementwise LSTM math.
#define B_ROWS 8192
#define D_DIM  1024
#define H_DIM  1024
#define K_DIM  2048

// Block = 256 threads = 4 waves (2x2). Tile: BM x BN of h/c = BM x 4*BN of gates.
#define BM 128
#define BN 64
#define BK 64

typedef __bf16 bf16x8 __attribute__((ext_vector_type(8)));
typedef float  f32x4  __attribute__((ext_vector_type(4)));
using bf16_t = __hip_bfloat16;

__device__ __forceinline__ float sigm(float x) {
  return 1.0f / (1.0f + __expf(-x));
}
__device__ __forceinline__ float tanh_fast(float x) {
  return 1.0f - 2.0f / (__expf(2.0f * x) + 1.0f);  // no inf/inf NaN
}

// ---- dtype probe -----------------------------------------------------------
// bf16-packed data: LOW 16 bits of each 32b word are a full bf16 normal sample
// -> exponent in [112,135] with p~0.9999. fp32 data: low 16 bits are random
// mantissa bits -> exponent field uniform -> p~0.094. 64 samples separate
// the two cases by >20 sigma. flag: 0 = bf16 I/O, 1 = fp32 I/O.
__global__ void detect_dtype(const unsigned int* __restrict__ xw,
                             int* __restrict__ flag) {
  const unsigned int w = xw[threadIdx.x & 63];
  const unsigned int lo_exp = (w >> 7) & 0xFFu;
  const int inr = (lo_exp >= 112u && lo_exp <= 135u) ? 1 : 0;
  const unsigned long long m = __ballot(inr);
  if (threadIdx.x == 0) *flag = (__popcll(m) >= 32) ? 0 : 1;
}

// ---- dtype-generic loads ---------------------------------------------------
template <bool F32>
__device__ __forceinline__ bf16x8 load8(const void* p, size_t off) {
  if constexpr (F32) {
    const float* f = (const float*)p + off;   // 32B-aligned (off % 8 == 0)
    const f32x4 a = *(const f32x4*)f;
    const f32x4 b = *(const f32x4*)(f + 4);
    bf16x8 r;
#pragma unroll
    for (int i = 0; i < 4; ++i) { r[i] = (__bf16)a[i]; r[i + 4] = (__bf16)b[i]; }
    return r;
  } else {
    return *(const bf16x8*)((const bf16_t*)p + off);
  }
}

template <bool F32>
__device__ __forceinline__ float ld_scalar(const void* p, size_t off) {
  if constexpr (F32) return ((const float*)p)[off];
  else return __bfloat162float(((const bf16_t*)p)[off]);
}

// ---- main fused kernel -----------------------------------------------------
template <bool F32>
__global__ __launch_bounds__(256, 2) void lstm_main(
    const void* __restrict__ xv, const void* __restrict__ hv,
    const void* __restrict__ cv, const void* __restrict__ wxv,
    const void* __restrict__ whv, const void* __restrict__ bv,
    void* __restrict__ outv, const int* __restrict__ flag) {
  if (*flag != (F32 ? 1 : 0)) return;  // uniform across grid: safe w/ barriers

  __shared__ bf16_t sA[BM * BK];        // 16 KB
  __shared__ bf16_t sB[4 * BN * BK];    // 32 KB (4 gate tiles)

  const int tid  = threadIdx.x;
  const int wave = tid >> 6;
  const int lane = tid & 63;
  const int m0 = blockIdx.x * BM;
  const int n0 = blockIdx.y * BN;

  const int wm = wave >> 1, wn = wave & 1;
  const int lr = lane & 15, quad = lane >> 4;

  f32x4 acc[4][4][2];
#pragma unroll
  for (int g = 0; g < 4; ++g)
#pragma unroll
    for (int ti = 0; ti < 4; ++ti)
#pragma unroll
      for (int tj = 0; tj < 2; ++tj) {
        f32x4 z = {0.0f, 0.0f, 0.0f, 0.0f};
        acc[g][ti][tj] = z;
      }

  // Staging: 48 1KB chunks (16 A + 32 B), chunk = 8 rows x 64 k bf16.
  // Lane L: row L/8, k-offset (L%8)*8 -> LDS chunk*512 + L*8 (row-major tile).
  const int srow = lane >> 3;
  const int scol = (lane & 7) * 8;

  for (int k0 = 0; k0 < K_DIM; k0 += BK) {
    const void* aSrc; const void* wSrc; int kh;
    if (k0 < D_DIM) { aSrc = xv; wSrc = wxv; kh = k0; }
    else            { aSrc = hv; wSrc = whv; kh = k0 - D_DIM; }

    __syncthreads();  // prior tile fully consumed before overwrite
#pragma unroll
    for (int t = 0; t < 12; ++t) {
      const int chunk = wave + t * 4;
      const void* src;
      size_t off;
      bf16_t* dst;
      if (chunk < 16) {
        const int row = chunk * 8 + srow;                    // 0..127
        src = aSrc;
        off = (size_t)(m0 + row) * 1024 + kh + scol;
        dst = &sA[chunk * 512 + lane * 8];
      } else {
        const int j = chunk - 16;                            // 0..31
        const int gate = j >> 3;
        const int row = (j & 7) * 8 + srow;                  // 0..63
        src = wSrc;
        off = (size_t)(gate * H_DIM + n0 + row) * 1024 + kh + scol;
        dst = &sB[j * 512 + lane * 8];
      }
      *(bf16x8*)dst = load8<F32>(src, off);   // ds_write_b128
    }
    __syncthreads();

#pragma unroll
    for (int kk = 0; kk < BK; kk += 32) {
      bf16x8 af[4];
#pragma unroll
      for (int ti = 0; ti < 4; ++ti)
        af[ti] = *(const bf16x8*)&sA[(wm * 64 + ti * 16 + lr) * BK + kk + quad * 8];
      bf16x8 bw[4][2];
#pragma unroll
      for (int g = 0; g < 4; ++g)
#pragma unroll
        for (int tj = 0; tj < 2; ++tj)
          bw[g][tj] = *(const bf16x8*)
              &sB[g * (BN * BK) + (wn * 32 + tj * 16 + lr) * BK + kk + quad * 8];
#pragma unroll
      for (int g = 0; g < 4; ++g)
#pragma unroll
        for (int ti = 0; ti < 4; ++ti)
#pragma unroll
          for (int tj = 0; tj < 2; ++tj)
            acc[g][ti][tj] = __builtin_amdgcn_mfma_f32_16x16x32_bf16(
                af[ti], bw[g][tj], acc[g][ti][tj], 0, 0, 0);
    }
  }

  // Epilogue: all 4 gates of (m,n) live in the same acc slot -> thread-local.
  // C/D layout: col = lane&15, row = quad*4 + reg.
  const size_t TOT = (size_t)B_ROWS * H_DIM;
#pragma unroll
  for (int tj = 0; tj < 2; ++tj) {
    const int n = n0 + wn * 32 + tj * 16 + lr;
    const float bi = ld_scalar<F32>(bv, n);
    const float bf = ld_scalar<F32>(bv, H_DIM + n);
    const float bo = ld_scalar<F32>(bv, 2 * H_DIM + n);
    const float bg = ld_scalar<F32>(bv, 3 * H_DIM + n);
#pragma unroll
    for (int ti = 0; ti < 4; ++ti) {
#pragma unroll
      for (int r = 0; r < 4; ++r) {
        const int m = m0 + wm * 64 + ti * 16 + quad * 4 + r;
        const size_t off = (size_t)m * H_DIM + n;
        const float iv = acc[0][ti][tj][r] + bi;
        const float fv = acc[1][ti][tj][r] + bf;
        const float ov = acc[2][ti][tj][r] + bo;
        const float gv = acc[3][ti][tj][r] + bg;
        const float cp = ld_scalar<F32>(cv, off);
        const float ct = sigm(fv) * cp + sigm(iv) * tanh_fast(gv);
        const float ht = sigm(ov) * tanh_fast(ct);
        if constexpr (F32) {
          ((float*)outv)[off] = ht;
          ((float*)outv)[TOT + off] = ct;
        } else {
          ((bf16_t*)outv)[off] = __float2bfloat16(ht);
          ((bf16_t*)outv)[TOT + off] = __float2bfloat16(ct);
        }
      }
    }
  }
}

extern "C" void kernel_launch(void* const* d_in, const int* in_sizes, int n_in,
                              void* d_out, int out_size, void* d_ws, size_t ws_size,
                              hipStream_t stream) {
  int* flag = (int*)d_ws;  // 4 bytes of scratch; recomputed every call
  detect_dtype<<<1, 64, 0, stream>>>((const unsigned int*)d_in[0], flag);

  dim3 grid(B_ROWS / BM, H_DIM / BN, 1);  // (64, 16)
  lstm_main<false><<<grid, 256, 0, stream>>>(d_in[0], d_in[1], d_in[2],
                                             d_in[3], d_in[4], d_in[5],
                                             d_out, flag);
  lstm_main<true><<<grid, 256, 0, stream>>>(d_in[0], d_in[1], d_in[2],
                                            d_in[3], d_in[4], d_in[5],
                                            d_out, flag);
}

// Round 3
// 366.996 us; speedup vs baseline: 1.0881x; 1.0881x over previous
//
#include <hip/hip_runtime.h>
#include <hip/hip_bf16.h>
#include <stdint.h>

// LSTMCell fused: gates[8192,4096] = x@Wx^T + h@Wh^T + b (one NT-GEMM,
// M=8192, N=4*1024 as 4 gate-tiles, K=2048 = concat[x|h]), then elementwise.
// I/O dtype: fp32 (established round 2: flag probe selected the fp32 variant;
// WRITE_SIZE=84MB matches fp32 outputs; round-0 bf16 interpretation NaN'd).
// Compute: bf16 MFMA 16x16x32 (absmax 0.0156 << 0.084 budget).
#define B_ROWS 8192
#define D_DIM  1024
#define H_DIM  1024
#define K_DIM  2048

// Block = 256 threads = 4 waves (2x2). Tile: BM x BN of h/c = BM x 4*BN gates.
#define BM 128
#define BN 64
#define BK 64

typedef __bf16 bf16x8 __attribute__((ext_vector_type(8)));
typedef float  f32x4  __attribute__((ext_vector_type(4)));

__device__ __forceinline__ float sigm(float x) {
  return 1.0f / (1.0f + __expf(-x));
}
__device__ __forceinline__ float tanh_fast(float x) {
  return 1.0f - 2.0f / (__expf(2.0f * x) + 1.0f);  // no inf/inf NaN
}

// LDS layout: row-major [row][64 cols] bf16, XOR-swizzled on 16B chunks:
// element offset = row*64 + ((col/8) ^ (row & 7))*8.
// Row stride = 128 B = 32 banks, so unswizzled frag-reads (16 lanes, same
// column chunk) were 16-way bank conflicts (the 3.78e7 SQ_LDS_BANK_CONFLICT
// in round 2). The XOR spreads the 16 rows of a quad across all 8 chunk
// positions -> 2 lanes/bank-group = free (m136).
__device__ __forceinline__ int sw(int row, int chunk) {
  return row * BK + ((chunk ^ (row & 7)) << 3);
}

__global__ __launch_bounds__(256, 2) void lstm_f32(
    const float* __restrict__ x, const float* __restrict__ h_prev,
    const float* __restrict__ c_prev, const float* __restrict__ Wx,
    const float* __restrict__ Wh, const float* __restrict__ bias,
    float* __restrict__ h_out, float* __restrict__ c_out) {
  __shared__ __hip_bfloat16 sA[BM * BK];        // 16 KB
  __shared__ __hip_bfloat16 sB[4 * BN * BK];    // 32 KB (4 gate tiles)

  const int tid  = threadIdx.x;
  const int wave = tid >> 6;
  const int lane = tid & 63;
  const int m0 = blockIdx.x * BM;   // 64 m-blocks (fastest: W tiles hot in L2)
  const int n0 = blockIdx.y * BN;   // 16 n-blocks

  const int wm = wave >> 1, wn = wave & 1;
  const int lr = lane & 15, quad = lane >> 4;

  f32x4 acc[4][4][2];
#pragma unroll
  for (int g = 0; g < 4; ++g)
#pragma unroll
    for (int ti = 0; ti < 4; ++ti)
#pragma unroll
      for (int tj = 0; tj < 2; ++tj) {
        f32x4 z = {0.0f, 0.0f, 0.0f, 0.0f};
        acc[g][ti][tj] = z;
      }

  // Staging decomposition: 48 chunks of (8 rows x 64 cols bf16) per K-step;
  // 16 A-chunks + 32 B-chunks; 12 chunks per wave. Lane L covers
  // row srow = L/8 of its chunk, cols scol..scol+7 where scol = (L%8)*8
  // (8 fp32 = 32 B global -> 8 bf16 = 16 B LDS).
  const int srow = lane >> 3;        // 0..7
  const int lc   = lane & 7;         // logical chunk-col
  const int scol = lc << 3;

  for (int k0 = 0; k0 < K_DIM; k0 += BK) {
    const float* aSrc; const float* wSrc; int kh;
    if (k0 < D_DIM) { aSrc = x;      wSrc = Wx; kh = k0; }
    else            { aSrc = h_prev; wSrc = Wh; kh = k0 - D_DIM; }

    // Issue this step's global loads BEFORE the barrier: latency overlaps the
    // other waves' MFMA tail. Rolling values live only through the barrier.
    f32x4 stg[12][2];
#pragma unroll
    for (int t = 0; t < 12; ++t) {
      const int chunk = wave + t * 4;
      const float* g;
      if (chunk < 16) {
        const int row = chunk * 8 + srow;                    // 0..127
        g = aSrc + (size_t)(m0 + row) * 1024 + kh + scol;
      } else {
        const int j = chunk - 16;                            // 0..31
        const int gate = j >> 3;
        const int row = (j & 7) * 8 + srow;                  // 0..63 in gate
        g = wSrc + (size_t)(gate * H_DIM + n0 + row) * 1024 + kh + scol;
      }
      stg[t][0] = *(const f32x4*)g;
      stg[t][1] = *(const f32x4*)(g + 4);
    }

    __syncthreads();  // previous tile fully consumed before overwrite

#pragma unroll
    for (int t = 0; t < 12; ++t) {
      const int chunk = wave + t * 4;
      bf16x8 v;
#pragma unroll
      for (int i = 0; i < 4; ++i) {
        v[i]     = (__bf16)stg[t][0][i];
        v[i + 4] = (__bf16)stg[t][1][i];
      }
      __hip_bfloat16* dst;
      if (chunk < 16) {
        const int row = chunk * 8 + srow;
        dst = &sA[sw(row, lc)];
      } else {
        const int j = chunk - 16;
        const int row = (j & 7) * 8 + srow;
        dst = &sB[(j >> 3) * (BN * BK) + sw(row, lc)];
      }
      *(bf16x8*)dst = v;   // ds_write_b128, per-row chunk permutation: no conflict
    }
    __syncthreads();

#pragma unroll
    for (int kk = 0; kk < BK; kk += 32) {
      const int cbase = kk >> 3;  // logical chunk of this k-half
      bf16x8 af[4];
#pragma unroll
      for (int ti = 0; ti < 4; ++ti)
        af[ti] = *(const bf16x8*)&sA[sw(wm * 64 + ti * 16 + lr, cbase + quad)];
      bf16x8 bw[4][2];
#pragma unroll
      for (int g = 0; g < 4; ++g)
#pragma unroll
        for (int tj = 0; tj < 2; ++tj)
          bw[g][tj] = *(const bf16x8*)
              &sB[g * (BN * BK) + sw(wn * 32 + tj * 16 + lr, cbase + quad)];
#pragma unroll
      for (int g = 0; g < 4; ++g)
#pragma unroll
        for (int ti = 0; ti < 4; ++ti)
#pragma unroll
          for (int tj = 0; tj < 2; ++tj)
            acc[g][ti][tj] = __builtin_amdgcn_mfma_f32_16x16x32_bf16(
                af[ti], bw[g][tj], acc[g][ti][tj], 0, 0, 0);
    }
    // top-of-loop barrier protects LDS overwrite next iteration
  }

  // Epilogue: all 4 gates of (m,n) live in the same acc slot -> thread-local.
  // C/D layout: col = lane&15, row = quad*4 + reg  (m89-verified).
  const size_t TOT = (size_t)B_ROWS * H_DIM;
#pragma unroll
  for (int tj = 0; tj < 2; ++tj) {
    const int n = n0 + wn * 32 + tj * 16 + lr;
    const float bi = bias[n];
    const float bf = bias[H_DIM + n];
    const float bo = bias[2 * H_DIM + n];
    const float bg = bias[3 * H_DIM + n];
#pragma unroll
    for (int ti = 0; ti < 4; ++ti) {
#pragma unroll
      for (int r = 0; r < 4; ++r) {
        const int m = m0 + wm * 64 + ti * 16 + quad * 4 + r;
        const size_t off = (size_t)m * H_DIM + n;
        const float iv = acc[0][ti][tj][r] + bi;
        const float fv = acc[1][ti][tj][r] + bf;
        const float ov = acc[2][ti][tj][r] + bo;
        const float gv = acc[3][ti][tj][r] + bg;
        const float cp = c_prev[off];
        const float ct = sigm(fv) * cp + sigm(iv) * tanh_fast(gv);
        const float ht = sigm(ov) * tanh_fast(ct);
        h_out[off] = ht;
        c_out[off] = ct;
      }
    }
  }
}

extern "C" void kernel_launch(void* const* d_in, const int* in_sizes, int n_in,
                              void* d_out, int out_size, void* d_ws, size_t ws_size,
                              hipStream_t stream) {
  const float* x      = (const float*)d_in[0];
  const float* h_prev = (const float*)d_in[1];
  const float* c_prev = (const float*)d_in[2];
  const float* Wx     = (const float*)d_in[3];
  const float* Wh     = (const float*)d_in[4];
  const float* b      = (const float*)d_in[5];
  float* h_out = (float*)d_out;
  float* c_out = (float*)d_out + (size_t)B_ROWS * H_DIM;

  dim3 grid(B_ROWS / BM, H_DIM / BN, 1);  // (64, 16)
  lstm_f32<<<grid, 256, 0, stream>>>(x, h_prev, c_prev, Wx, Wh, b, h_out, c_out);
}

// Round 4
// 312.847 us; speedup vs baseline: 1.2764x; 1.1731x over previous
//
#include <hip/hip_runtime.h>
#include <hip/hip_bf16.h>
#include <stdint.h>

// LSTMCell fused: gates[8192,4096] = x@Wx^T + h@Wh^T + b as one NT-GEMM
// (M=8192, N=4096 via 4 gate-tiles, K=2048 = concat[x|h]), then elementwise.
// I/O: fp32 (established r2). Compute: bf16 MFMA 16x16x32 (absmax 0.0156).
//
// r3 post-mortem: LDS-BW-bound (144 KB/block-step vs 310 MFMA cyc -> 18%
// MfmaUtil, matches model). This round: pre-pack inputs to bf16 in d_ws in
// MFMA-frag-linear 1KB chunks, then m97-style global_load_lds staging:
// no ds_writes, no in-loop cvt, conflict-free b128 frag reads.
#define B_ROWS 8192
#define D_DIM  1024
#define H_DIM  1024
#define K_DIM  2048
#define N_GATES 4096

#define BM 128
#define BN 64   // h/c columns per block -> 256 gate-columns
#define BK 64

#define KC (K_DIM / 32)        // 64 k-chunks of 32
#define A_M16 (B_ROWS / 16)    // 512 row-chunks
#define W_N16 (N_GATES / 16)   // 256 gate-row-chunks
#define A_CHUNKS (A_M16 * KC)  // 32768
#define W_CHUNKS (W_N16 * KC)  // 16384
#define A_WS_BYTES ((size_t)A_CHUNKS * 1024)
#define W_WS_BYTES ((size_t)W_CHUNKS * 1024)

typedef __bf16 bf16x8 __attribute__((ext_vector_type(8)));
typedef float  f32x4  __attribute__((ext_vector_type(4)));
using bf16_t = __hip_bfloat16;

__device__ __forceinline__ float sigm(float x) {
  return 1.0f / (1.0f + __expf(-x));
}
__device__ __forceinline__ float tanh_fast(float x) {
  return 1.0f - 2.0f / (__expf(2.0f * x) + 1.0f);  // no inf/inf NaN
}

__device__ __forceinline__ void async_ld16(const void* g, void* l) {
  __builtin_amdgcn_global_load_lds(
      (const __attribute__((address_space(1))) unsigned int*)g,
      (__attribute__((address_space(3))) unsigned int*)l, 16, 0, 0);
}

// ---- pack: fp32 inputs -> bf16, MFMA-frag-linear chunks -------------------
// Chunk = 16 rows x 32 k. Element (lane, j): row = base+ (lane&15),
// k = kbase + (lane>>4)*8 + j. Stored at chunk*1024B + lane*16B + j*2B.
// This IS the 16x16x32 MFMA A/B operand layout, so the main kernel's frag
// read is ds_read_b128 at chunkbase + lane*16: linear, conflict-free.
__global__ void pack_tiles(const float* __restrict__ x,
                           const float* __restrict__ h,
                           const float* __restrict__ Wx,
                           const float* __restrict__ Wh,
                           bf16_t* __restrict__ aws,
                           bf16_t* __restrict__ wws) {
  const int wave = threadIdx.x >> 6, lane = threadIdx.x & 63;
  int c = blockIdx.x * 4 + wave;   // 49152 chunks total, exact grid
  const int r16 = lane & 15, quad = lane >> 4;
  const float* src;
  size_t soff;
  bf16_t* dst;
  if (c < A_CHUNKS) {
    const int m16 = c / KC, k32 = c % KC;
    const int k = k32 * 32 + quad * 8;      // no x/h straddle: 32 | 1024
    src = (k < D_DIM) ? x : h;
    soff = (size_t)(m16 * 16 + r16) * 1024 + (k & 1023);
    dst = aws + (size_t)c * 512;
  } else {
    c -= A_CHUNKS;
    const int n16 = c / KC, k32 = c % KC;
    const int k = k32 * 32 + quad * 8;
    src = (k < D_DIM) ? Wx : Wh;
    soff = (size_t)(n16 * 16 + r16) * 1024 + (k & 1023);
    dst = wws + (size_t)c * 512;
  }
  const f32x4 a = *(const f32x4*)(src + soff);
  const f32x4 b = *(const f32x4*)(src + soff + 4);
  bf16x8 v;
#pragma unroll
  for (int i = 0; i < 4; ++i) { v[i] = (__bf16)a[i]; v[i + 4] = (__bf16)b[i]; }
  *(bf16x8*)(dst + lane * 8) = v;   // 1 KB/wave contiguous store
}

// ---- main: DMA-staged bf16 MFMA GEMM + fused LSTM epilogue ----------------
__global__ __launch_bounds__(256, 2) void lstm_mfma(
    const bf16_t* __restrict__ aws, const bf16_t* __restrict__ wws,
    const float* __restrict__ c_prev, const float* __restrict__ bias,
    float* __restrict__ h_out, float* __restrict__ c_out) {
  __shared__ bf16_t sA[16 * 512];   // 16 chunks: (mi 0..7) x (kq 0..1), 16 KB
  __shared__ bf16_t sB[32 * 512];   // 32 chunks: (ni 0..15) x (kq 0..1), 32 KB

  const int tid  = threadIdx.x;
  const int wave = tid >> 6;
  const int lane = tid & 63;
  const int m0 = blockIdx.x * BM;   // 64 m-blocks fastest -> W hot in L2
  const int n0 = blockIdx.y * BN;

  const int wm = wave >> 1, wn = wave & 1;
  const int lr = lane & 15, quad = lane >> 4;
  const int m16_0 = m0 >> 4;
  const int n16_0 = n0 >> 4;

  f32x4 acc[4][4][2];
#pragma unroll
  for (int g = 0; g < 4; ++g)
#pragma unroll
    for (int ti = 0; ti < 4; ++ti)
#pragma unroll
      for (int tj = 0; tj < 2; ++tj) {
        f32x4 z = {0.0f, 0.0f, 0.0f, 0.0f};
        acc[g][ti][tj] = z;
      }

  for (int k0 = 0; k0 < K_DIM; k0 += BK) {
    const int kq0 = k0 >> 5;   // two k32-chunks per step

    __syncthreads();  // all waves done reading previous tile
    // 48 DMA chunks (16 A + 32 B), 12 per wave, 16 B/lane each.
#pragma unroll
    for (int t = 0; t < 12; ++t) {
      const int ch = t * 4 + wave;
      const bf16_t* g;
      bf16_t* l;
      if (ch < 16) {
        const int mi = ch >> 1, kq = ch & 1;
        g = aws + ((size_t)(m16_0 + mi) * KC + kq0 + kq) * 512;
        l = sA + ch * 512;
      } else {
        const int j = ch - 16;             // 0..31
        const int ni = j >> 1, kq = j & 1; // ni = gate*4 + ii
        const int n16 = (ni >> 2) * (H_DIM / 16) + n16_0 + (ni & 3);
        g = wws + ((size_t)n16 * KC + kq0 + kq) * 512;
        l = sB + j * 512;
      }
      async_ld16(g + lane * 8, l + lane * 8);
    }
    __syncthreads();  // vmcnt(0) drained before barrier -> tiles ready

#pragma unroll
    for (int kq = 0; kq < 2; ++kq) {
      bf16x8 af[4];
#pragma unroll
      for (int ti = 0; ti < 4; ++ti)
        af[ti] = *(const bf16x8*)&sA[((wm * 4 + ti) * 2 + kq) * 512 + lane * 8];
      bf16x8 bw[4][2];
#pragma unroll
      for (int g = 0; g < 4; ++g)
#pragma unroll
        for (int tj = 0; tj < 2; ++tj)
          bw[g][tj] = *(const bf16x8*)
              &sB[((g * 4 + wn * 2 + tj) * 2 + kq) * 512 + lane * 8];
#pragma unroll
      for (int g = 0; g < 4; ++g)
#pragma unroll
        for (int ti = 0; ti < 4; ++ti)
#pragma unroll
          for (int tj = 0; tj < 2; ++tj)
            acc[g][ti][tj] = __builtin_amdgcn_mfma_f32_16x16x32_bf16(
                af[ti], bw[g][tj], acc[g][ti][tj], 0, 0, 0);
    }
  }

  // Epilogue: 4 gates of (m,n) share an acc slot -> thread-local.
  // C/D layout: col = lane&15, row = quad*4 + reg (m89-verified; r2/r3 pass).
  const size_t TOT = (size_t)B_ROWS * H_DIM;
#pragma unroll
  for (int tj = 0; tj < 2; ++tj) {
    const int n = n0 + wn * 32 + tj * 16 + lr;
    const float bi = bias[n];
    const float bf = bias[H_DIM + n];
    const float bo = bias[2 * H_DIM + n];
    const float bg = bias[3 * H_DIM + n];
#pragma unroll
    for (int ti = 0; ti < 4; ++ti) {
#pragma unroll
      for (int r = 0; r < 4; ++r) {
        const int m = m0 + wm * 64 + ti * 16 + quad * 4 + r;
        const size_t off = (size_t)m * H_DIM + n;
        const float iv = acc[0][ti][tj][r] + bi;
        const float fv = acc[1][ti][tj][r] + bf;
        const float ov = acc[2][ti][tj][r] + bo;
        const float gv = acc[3][ti][tj][r] + bg;
        const float cp = c_prev[off];
        const float ct = sigm(fv) * cp + sigm(iv) * tanh_fast(gv);
        const float ht = sigm(ov) * tanh_fast(ct);
        h_out[off] = ht;
        c_out[off] = ct;
      }
    }
  }
}

// ---- fallback (r3 kernel): used only if ws_size is too small --------------
__device__ __forceinline__ int sw_(int row, int chunk) {
  return row * BK + ((chunk ^ (row & 7)) << 3);
}

__global__ __launch_bounds__(256, 2) void lstm_f32(
    const float* __restrict__ x, const float* __restrict__ h_prev,
    const float* __restrict__ c_prev, const float* __restrict__ Wx,
    const float* __restrict__ Wh, const float* __restrict__ bias,
    float* __restrict__ h_out, float* __restrict__ c_out) {
  __shared__ bf16_t sA[BM * BK];
  __shared__ bf16_t sB[4 * BN * BK];
  const int tid = threadIdx.x, wave = tid >> 6, lane = tid & 63;
  const int m0 = blockIdx.x * BM, n0 = blockIdx.y * BN;
  const int wm = wave >> 1, wn = wave & 1;
  const int lr = lane & 15, quad = lane >> 4;
  f32x4 acc[4][4][2];
#pragma unroll
  for (int g = 0; g < 4; ++g)
#pragma unroll
    for (int ti = 0; ti < 4; ++ti)
#pragma unroll
      for (int tj = 0; tj < 2; ++tj) {
        f32x4 z = {0.0f, 0.0f, 0.0f, 0.0f};
        acc[g][ti][tj] = z;
      }
  const int srow = lane >> 3, lc = lane & 7, scol = lc << 3;
  for (int k0 = 0; k0 < K_DIM; k0 += BK) {
    const float* aSrc; const float* wSrc; int kh;
    if (k0 < D_DIM) { aSrc = x; wSrc = Wx; kh = k0; }
    else            { aSrc = h_prev; wSrc = Wh; kh = k0 - D_DIM; }
    f32x4 stg[12][2];
#pragma unroll
    for (int t = 0; t < 12; ++t) {
      const int chunk = wave + t * 4;
      const float* g;
      if (chunk < 16) {
        g = aSrc + (size_t)(m0 + chunk * 8 + srow) * 1024 + kh + scol;
      } else {
        const int j = chunk - 16;
        g = wSrc + (size_t)((j >> 3) * H_DIM + n0 + (j & 7) * 8 + srow) * 1024 + kh + scol;
      }
      stg[t][0] = *(const f32x4*)g;
      stg[t][1] = *(const f32x4*)(g + 4);
    }
    __syncthreads();
#pragma unroll
    for (int t = 0; t < 12; ++t) {
      const int chunk = wave + t * 4;
      bf16x8 v;
#pragma unroll
      for (int i = 0; i < 4; ++i) {
        v[i] = (__bf16)stg[t][0][i];
        v[i + 4] = (__bf16)stg[t][1][i];
      }
      bf16_t* dst;
      if (chunk < 16) dst = &sA[sw_(chunk * 8 + srow, lc)];
      else {
        const int j = chunk - 16;
        dst = &sB[(j >> 3) * (BN * BK) + sw_((j & 7) * 8 + srow, lc)];
      }
      *(bf16x8*)dst = v;
    }
    __syncthreads();
#pragma unroll
    for (int kk = 0; kk < BK; kk += 32) {
      const int cbase = kk >> 3;
      bf16x8 af[4];
#pragma unroll
      for (int ti = 0; ti < 4; ++ti)
        af[ti] = *(const bf16x8*)&sA[sw_(wm * 64 + ti * 16 + lr, cbase + quad)];
      bf16x8 bw[4][2];
#pragma unroll
      for (int g = 0; g < 4; ++g)
#pragma unroll
        for (int tj = 0; tj < 2; ++tj)
          bw[g][tj] = *(const bf16x8*)
              &sB[g * (BN * BK) + sw_(wn * 32 + tj * 16 + lr, cbase + quad)];
#pragma unroll
      for (int g = 0; g < 4; ++g)
#pragma unroll
        for (int ti = 0; ti < 4; ++ti)
#pragma unroll
          for (int tj = 0; tj < 2; ++tj)
            acc[g][ti][tj] = __builtin_amdgcn_mfma_f32_16x16x32_bf16(
                af[ti], bw[g][tj], acc[g][ti][tj], 0, 0, 0);
    }
  }
  const size_t TOT = (size_t)B_ROWS * H_DIM;
#pragma unroll
  for (int tj = 0; tj < 2; ++tj) {
    const int n = n0 + wn * 32 + tj * 16 + lr;
    const float bi = bias[n], bf = bias[H_DIM + n];
    const float bo = bias[2 * H_DIM + n], bg = bias[3 * H_DIM + n];
#pragma unroll
    for (int ti = 0; ti < 4; ++ti)
#pragma unroll
      for (int r = 0; r < 4; ++r) {
        const int m = m0 + wm * 64 + ti * 16 + quad * 4 + r;
        const size_t off = (size_t)m * H_DIM + n;
        const float iv = acc[0][ti][tj][r] + bi;
        const float fv = acc[1][ti][tj][r] + bf;
        const float ov = acc[2][ti][tj][r] + bo;
        const float gv = acc[3][ti][tj][r] + bg;
        const float cp = c_prev[off];
        const float ct = sigm(fv) * cp + sigm(iv) * tanh_fast(gv);
        h_out[off] = sigm(ov) * tanh_fast(ct);
        c_out[off] = ct;
      }
  }
}

extern "C" void kernel_launch(void* const* d_in, const int* in_sizes, int n_in,
                              void* d_out, int out_size, void* d_ws, size_t ws_size,
                              hipStream_t stream) {
  const float* x      = (const float*)d_in[0];
  const float* h_prev = (const float*)d_in[1];
  const float* c_prev = (const float*)d_in[2];
  const float* Wx     = (const float*)d_in[3];
  const float* Wh     = (const float*)d_in[4];
  const float* b      = (const float*)d_in[5];
  float* h_out = (float*)d_out;
  float* c_out = (float*)d_out + (size_t)B_ROWS * H_DIM;

  dim3 grid(B_ROWS / BM, H_DIM / BN, 1);  // (64, 16)
  if (ws_size >= A_WS_BYTES + W_WS_BYTES) {
    bf16_t* aws = (bf16_t*)d_ws;
    bf16_t* wws = (bf16_t*)((char*)d_ws + A_WS_BYTES);
    pack_tiles<<<(A_CHUNKS + W_CHUNKS) / 4, 256, 0, stream>>>(x, h_prev, Wx, Wh,
                                                              aws, wws);
    lstm_mfma<<<grid, 256, 0, stream>>>(aws, wws, c_prev, b, h_out, c_out);
  } else {
    lstm_f32<<<grid, 256, 0, stream>>>(x, h_prev, c_prev, Wx, Wh, b, h_out, c_out);
  }
}